// Round 21
// baseline (1208.697 us; speedup 1.0000x reference)
//
#include <hip/hip_runtime.h>
#include <math.h>

#define BB 8
#define S 256
#define CIN 3
#define W64 64
#define MODES 32
#define PP 34     // MODES + BW - 1
#define KPAD 36   // padded leading dim for f32 Dt
#define KPB 40    // padded leading dim for bf16 Dt tables (16B-aligned frag loads)

typedef __attribute__((ext_vector_type(8))) short bfrag;    // 8 bf16 raw bits
typedef __attribute__((ext_vector_type(16))) float f32x16;

// fast erf-based gelu: A&S 7.1.26, |erf err| <= 1.5e-7 (libm erff is ~40 insts)
__device__ __forceinline__ float gelu_f(float x){
    float z = fabsf(x) * 0.70710678118654752f;
    float t = 1.0f / (1.0f + 0.3275911f * z);
    float p = ((((1.061405429f * t - 1.453152027f) * t) + 1.421413741f) * t
               - 0.284496736f) * t + 0.254829592f;
    float e = __expf(-z * z);
    float erf = 1.0f - p * t * e;
    erf = copysignf(erf, x);
    return 0.5f * x * (1.0f + erf);
}

// accurate split (round-to-nearest hi): used in one-time weight/DT prep
__device__ __forceinline__ void split_bf(float x, short &hi, short &lo){
    unsigned u = __float_as_uint(x);
    unsigned r = u + 0x7FFFu + ((u >> 16) & 1u);
    hi = (short)(r >> 16);
    float hf = __uint_as_float(r & 0xFFFF0000u);
    float l = x - hf;
    unsigned v = __float_as_uint(l);
    unsigned s2 = v + 0x7FFFu + ((v >> 16) & 1u);
    lo = (short)(s2 >> 16);
}

// fast split (truncated hi): per-dispatch hot staging paths. err <= 2^-15 |x|.
__device__ __forceinline__ void split_bf_fast(float x, short &hi, short &lo){
    unsigned u = __float_as_uint(x);
    hi = (short)(u >> 16);
    float hf = __uint_as_float(u & 0xFFFF0000u);
    float l = x - hf;
    unsigned v = __float_as_uint(l);
    unsigned s2 = v + 0x7FFFu + ((v >> 16) & 1u);
    lo = (short)(s2 >> 16);
}

// split 8 floats (two float4) into hi/lo bfrags (fast variant)
__device__ __forceinline__ void split8(float4 a, float4 b, bfrag &hv, bfrag &lv){
    short hi, lo;
    split_bf_fast(a.x, hi, lo); hv[0] = hi; lv[0] = lo;
    split_bf_fast(a.y, hi, lo); hv[1] = hi; lv[1] = lo;
    split_bf_fast(a.z, hi, lo); hv[2] = hi; lv[2] = lo;
    split_bf_fast(a.w, hi, lo); hv[3] = hi; lv[3] = lo;
    split_bf_fast(b.x, hi, lo); hv[4] = hi; lv[4] = lo;
    split_bf_fast(b.y, hi, lo); hv[5] = hi; lv[5] = lo;
    split_bf_fast(b.z, hi, lo); hv[6] = hi; lv[6] = lo;
    split_bf_fast(b.w, hi, lo); hv[7] = hi; lv[7] = lo;
}

__device__ __forceinline__ float bf2f(short s){
    return __uint_as_float(((unsigned)(unsigned short)s) << 16);
}

// dt[h*36+k] = DCT[k,h] f32; dth/dtl[h*40+k] = bf16 hi/lo split
__global__ void k_init_dt(float* __restrict__ dt, short* __restrict__ dth,
                          short* __restrict__ dtl){
    int tid = blockIdx.x * 256 + threadIdx.x;
    if (tid >= S * KPB) return;
    int h = tid / KPB, k = tid % KPB;
    double v = 0.0;
    if (k < PP) {
        v = sqrt(2.0 / (double)S) * cos(3.14159265358979323846 * (h + 0.5) * k / (double)S);
        if (k == 0) v *= 0.70710678118654752440;
    }
    float f = (float)v;
    if (k < KPAD) dt[h * KPAD + k] = f;
    short hi, lo; split_bf(f, hi, lo);
    dth[tid] = hi; dtl[tid] = lo;
}

// split a 64x64 conv weight into bf16 hi/lo (layout preserved: pw[o][i])
__global__ void k_prep_pw(const float* __restrict__ pw, short* __restrict__ pwh,
                          short* __restrict__ pwl){
    int e = blockIdx.x * 256 + threadIdx.x;
    if (e >= 4096) return;
    short hi, lo; split_bf(pw[e], hi, lo);
    pwh[e] = hi; pwl[e] = lo;
}

// split fc1 (64 i x 128 j) into B-fragment-ordered hi/lo
__global__ void k_prep_fc1(const float* __restrict__ fc1w, short* __restrict__ f1h,
                           short* __restrict__ f1l){
    int e = blockIdx.x * 256 + threadIdx.x;
    if (e >= 8192) return;
    int i = e >> 7, j = e & 127;
    int n = j >> 5, ks = i >> 4;
    int l = (j & 31) + (((i & 15) >= 8) ? 32 : 0);
    int jr = i & 7;
    int idx = ((n * 4 + ks) * 64 + l) * 8 + jr;
    short hi, lo; split_bf(fc1w[e], hi, lo);
    f1h[idx] = hi; f1l[idx] = lo;
}

// x (B,S,S,3) -> h channels 0..2 (channels-last h: (B,S,S,64))
__global__ void k_copy_x(const float* __restrict__ x, float* __restrict__ h){
    int e = blockIdx.x * 256 + threadIdx.x;
    if (e >= BB * S * S * CIN) return;
    int px = e / CIN, c = e % CIN;
    h[(size_t)px * W64 + c] = x[e];
}

// tmp1[b][k][w][c] = sum_h Dt[h][k] * src[b][h][w][c]   (C=3, block0 path)
template<int C>
__global__ void k_fwd1(const float* __restrict__ src, float* __restrict__ tmp1,
                       const float* __restrict__ dt){
    int b = blockIdx.y;
    int idx = blockIdx.x * 256 + threadIdx.x;   // flat (w, c)
    if (idx >= S * C) return;
    float acc[PP];
    #pragma unroll
    for (int k = 0; k < PP; k++) acc[k] = 0.f;
    const float* sp = src + (size_t)b * S * S * C + idx;
    for (int hh = 0; hh < S; hh++){
        float v = sp[(size_t)hh * S * C];
        const float* dr = dt + hh * KPAD;
        #pragma unroll
        for (int k = 0; k < PP; k++) acc[k] = fmaf(dr[k], v, acc[k]);
    }
    float* op = tmp1 + (size_t)b * PP * S * C + idx;
    #pragma unroll
    for (int k = 0; k < PP; k++) op[(size_t)k * S * C] = acc[k];
}

// C=64, h-split: half hf reduces h in [hf*128, hf*128+128) -> tmp1 + hf*TM1.
__global__ void k_fwd1_64s(const float* __restrict__ src, float* __restrict__ tmp1,
                           const float* __restrict__ dt){
    const int C = 64;
    const size_t TM1 = (size_t)BB * PP * S * C;
    int b = blockIdx.z, hf = blockIdx.y;
    int idx = blockIdx.x * 256 + threadIdx.x;   // flat (w, c)
    float acc[PP];
    #pragma unroll
    for (int k = 0; k < PP; k++) acc[k] = 0.f;
    const float* sp = src + (size_t)b * S * S * C + (size_t)hf * 128 * S * C + idx;
    for (int hh = 0; hh < 128; hh++){
        float v = sp[(size_t)hh * S * C];
        const float* dr = dt + (hf * 128 + hh) * KPAD;
        #pragma unroll
        for (int k = 0; k < PP; k++) acc[k] = fmaf(dr[k], v, acc[k]);
    }
    float* op = tmp1 + (size_t)hf * TM1 + (size_t)b * PP * S * C + idx;
    #pragma unroll
    for (int k = 0; k < PP; k++) op[(size_t)k * S * C] = acc[k];
}

// bp[b][k][l][c] = sum_w Dt[w][l] * tmp1[b][k][w][c]   (C=3 path, tiny)
__global__ void k_fwd2_3(const float* __restrict__ tmp1, float* __restrict__ bp,
                         const float* __restrict__ dt){
    const int C = 3;
    int b = blockIdx.y;
    int idx = blockIdx.x * 256 + threadIdx.x;   // flat (k, c)
    if (idx >= PP * C) return;
    int k = idx / C, c = idx % C;
    float acc[PP];
    #pragma unroll
    for (int l = 0; l < PP; l++) acc[l] = 0.f;
    const float* sp = tmp1 + ((size_t)b * PP + k) * S * C + c;
    for (int w = 0; w < S; w++){
        float v = sp[(size_t)w * C];
        const float* dr = dt + w * KPAD;
        #pragma unroll
        for (int l = 0; l < PP; l++) acc[l] = fmaf(dr[l], v, acc[l]);
    }
    float* op = bp + ((size_t)b * PP + k) * PP * C + c;
    #pragma unroll
    for (int l = 0; l < PP; l++) op[(size_t)l * C] = acc[l];
}

// C=64: block = (k, b), 4 waves each own a 64-wide w-segment, LDS reduce.
// Sums the two tmp1 h-halves while streaming.
__global__ __launch_bounds__(256, 4) void k_fwd2_64(
        const float* __restrict__ tmp1, float* __restrict__ bp,
        const float* __restrict__ dt){
    const int C = 64;
    const size_t TM1 = (size_t)BB * PP * S * C;
    __shared__ float red[4 * PP * 66];   // 35.9 KB
    int k = blockIdx.x, b = blockIdx.y;
    int t = threadIdx.x;
    int c = t & 63;
    int ws = __builtin_amdgcn_readfirstlane(t >> 6);
    float acc[PP];
    #pragma unroll
    for (int l = 0; l < PP; l++) acc[l] = 0.f;
    const float* sp = tmp1 + ((size_t)b * PP + k) * S * C + c;
    for (int w = ws * 64; w < ws * 64 + 64; w++){
        float v = sp[(size_t)w * C] + sp[TM1 + (size_t)w * C];
        const float* dr = dt + w * KPAD;
        #pragma unroll
        for (int l = 0; l < PP; l++) acc[l] = fmaf(dr[l], v, acc[l]);
    }
    #pragma unroll
    for (int l = 0; l < PP; l++) red[(ws * PP + l) * 66 + c] = acc[l];
    __syncthreads();
    float* op = bp + ((size_t)b * PP + k) * PP * C;
    for (int e = t; e < PP * C; e += 256){
        int l = e >> 6, cc = e & 63;
        op[e] = red[(0 * PP + l) * 66 + cc] + red[(1 * PP + l) * 66 + cc]
              + red[(2 * PP + l) * 66 + cc] + red[(3 * PP + l) * 66 + cc];
    }
}

// xp[i][kl][b] = bp[b][k+i_][l+j_][c],  i = c*9 + i_*3 + j_, kl = k*32 + l
template<int C, int CC>
__global__ void k_xp_gather(const float* __restrict__ bp, float* __restrict__ xp){
    __shared__ float lds[8 * 3 * PP * (CC + 1)];
    int k  = blockIdx.x;           // 0..31
    int c0 = blockIdx.y * CC;
    int t  = threadIdx.x;
    const int TOT = 8 * 3 * PP * CC;
    for (int e = t; e < TOT; e += 256){
        int b   = e / (3 * PP * CC);
        int r   = e % (3 * PP * CC);
        int row = r / (PP * CC);
        int r2  = r % (PP * CC);
        int l   = r2 / CC;
        int c   = r2 % CC;
        lds[((b * 3 + row) * PP + l) * (CC + 1) + c] =
            bp[(((size_t)b * PP + (k + row)) * PP + l) * C + c0 + c];
    }
    __syncthreads();
    int l = t >> 3;   // 0..31
    int b = t & 7;
    for (int c = 0; c < CC; c++){
        #pragma unroll
        for (int ij = 0; ij < 9; ij++){
            int i_ = ij / 3, j_ = ij % 3;
            int i  = (c0 + c) * 9 + ij;
            float v = lds[((b * 3 + i_) * PP + (l + j_)) * (CC + 1) + c];
            xp[((size_t)i * 1024 + k * 32 + l) * 8 + b] = v;
        }
    }
}

// part[ns][b][o][kl] = sum_{i in slice ns} xp[i][kl][b] * w[i][o][kl]
// NS slices: NS=8 for the 576-i path -> 2048 blocks = 8 blocks/CU (the old
// 3-slice grid of 768 capped occupancy at 3 blocks/CU = 37%, leaving the
// 151MB weight stream latency-bound at ~2.3 TB/s).
template<int ITOT, int O, int NS>
__global__ void k_om(const float* __restrict__ xp, const float* __restrict__ w,
                     float* __restrict__ part){
    int bx  = blockIdx.x;
    int klt = bx & 31;
    int ot  = (bx >> 5) & 7;
    int ns  = bx >> 8;              // 0..NS-1
    const int ILEN = ITOT / NS;
    int t  = threadIdx.x;
    int kl = klt * 32 + (t & 31);
    int o  = ot * 8 + (t >> 5);
    if (o >= O) return;
    float a0=0,a1=0,a2=0,a3=0,a4=0,a5=0,a6=0,a7=0;
    const float* xpp = xp + ((size_t)(ns * ILEN) * 1024 + kl) * 8;
    const float* wp  = w + ((size_t)(ns * ILEN) * O + o) * 1024 + kl;
    #pragma unroll 4
    for (int i = 0; i < ILEN; i++){
        float4 xa = *(const float4*)(xpp + (size_t)i * 8192);
        float4 xb = *(const float4*)(xpp + (size_t)i * 8192 + 4);
        float wv  = wp[(size_t)i * O * 1024];
        a0 = fmaf(xa.x, wv, a0); a1 = fmaf(xa.y, wv, a1);
        a2 = fmaf(xa.z, wv, a2); a3 = fmaf(xa.w, wv, a3);
        a4 = fmaf(xb.x, wv, a4); a5 = fmaf(xb.y, wv, a5);
        a6 = fmaf(xb.z, wv, a6); a7 = fmaf(xb.w, wv, a7);
    }
    float* pp = part + (size_t)ns * 8 * 64 * 1024;
    pp[((size_t)0 * 64 + o) * 1024 + kl] = a0;
    pp[((size_t)1 * 64 + o) * 1024 + kl] = a1;
    pp[((size_t)2 * 64 + o) * 1024 + kl] = a2;
    pp[((size_t)3 * 64 + o) * 1024 + kl] = a3;
    pp[((size_t)4 * 64 + o) * 1024 + kl] = a4;
    pp[((size_t)5 * 64 + o) * 1024 + kl] = a5;
    pp[((size_t)6 * 64 + o) * 1024 + kl] = a6;
    pp[((size_t)7 * 64 + o) * 1024 + kl] = a7;
}

// t2[b][k][w][o] = sum_l Dt[w][l] * om[b][o][k*32+l]; om = sum of NS part slices
template<int O, int NS>
__global__ void k_inv1(const float* __restrict__ part, float* __restrict__ t2,
                       const float* __restrict__ dt){
    __shared__ float oms[32 * 65];
    const int N = 8 * 64 * 1024;
    int wc = blockIdx.x, k = blockIdx.y, b = blockIdx.z;
    int t = threadIdx.x;
    for (int e = t; e < 2048; e += 256){
        int o_ = e >> 5, l = e & 31;
        int idx = ((b * 64 + o_) << 10) + k * 32 + l;
        float s = 0.f;
        #pragma unroll
        for (int sl = 0; sl < NS; sl++) s += part[(size_t)sl * N + idx];
        oms[l * 65 + o_] = s;
    }
    __syncthreads();
    int o  = t & 63;
    int wg = __builtin_amdgcn_readfirstlane(t >> 6);
    int wbase = wc * 32 + wg * 8;
    float acc[8];
    #pragma unroll
    for (int wj = 0; wj < 8; wj++) acc[wj] = 0.f;
    for (int l = 0; l < 32; l++){
        float ov = oms[l * 65 + o];
        #pragma unroll
        for (int wj = 0; wj < 8; wj++)
            acc[wj] = fmaf(dt[(wbase + wj) * KPAD + l], ov, acc[wj]);
    }
    if (o < O){
        #pragma unroll
        for (int wj = 0; wj < 8; wj++)
            t2[(((size_t)b * 32 + k) * S + wbase + wj) * 64 + o] = acc[wj];
    }
}

// MFMA k_fused v5 (R16 structure, best measured): ht-loop, t2 B-frags in
// registers (ht-invariant), hsf double-buffered, one barrier per ht,
// residual reconstructed from hsf hi/lo pair. LDS 32KB.
template<bool CONV>
__global__ __launch_bounds__(256, 4) void k_fused(
        const float* __restrict__ t2, float* __restrict__ h,
        const short* __restrict__ pwh, const short* __restrict__ pwl,
        const float* __restrict__ pb,
        const short* __restrict__ dth, const short* __restrict__ dtl){
    __shared__ short hsfh[CONV ? 2 * 8 * 64 * 8 : 1];      // [buf][g][row^g][j]
    __shared__ short hsfl[CONV ? 2 * 8 * 64 * 8 : 1];
    int wt = blockIdx.x, b = blockIdx.y;
    int t = threadIdx.x;
    int l = t & 63;
    int n = t >> 6;
    int oh = n & 1, wl = n >> 1;
    int o = oh * 32 + (l & 31);

    // ---- t2 B-fragments direct to regs (ht-invariant)
    bfrag t2h[2], t2l[2];
    {
        const float* tp = t2 + ((size_t)(b * 32 + (l >> 5) * 8) * S + wt * 2 + wl) * 64 + o;
        #pragma unroll
        for (int ks = 0; ks < 2; ks++){
            #pragma unroll
            for (int j = 0; j < 8; j++){
                short hi, lo;
                split_bf_fast(tp[(size_t)(ks * 16 + j) * S * 64], hi, lo);
                t2h[ks][j] = hi; t2l[ks][j] = lo;
            }
        }
    }

    // residual-reconstruct constants (fixed per thread)
    int g_res = wl * 4 + (o >> 4);
    int jres  = o & 7;
    int rowadd = ((o & 15) >= 8) ? 32 : 0;

    // prefetch geometry: task A = (pxA, ihalf), task B = (pxA+32, ihalf)
    int ihalf = t & 7;
    int pxA = t >> 3;          // 0..31
    int pxB = pxA + 32;        // 32..63
    const float* hb = h + ((size_t)b * S * S + (size_t)wt * 2) * 64;
    size_t offA = ((size_t)(pxA >> 1) * S + (pxA & 1)) * 64 + ihalf * 8;
    size_t offB = ((size_t)(pxB >> 1) * S + (pxB & 1)) * 64 + ihalf * 8;
    float4 a0, a1, b0, b1;
    if (CONV){
        a0 = *(const float4*)(hb + offA);
        a1 = *(const float4*)(hb + offA + 4);
        b0 = *(const float4*)(hb + offB);
        b1 = *(const float4*)(hb + offB + 4);
    }

    int cur = 0;
    for (int ht = 0; ht < 8; ht++){
        if (CONV){
            // write hsf[cur] from prefetched regs (swizzled b128)
            int ks = ihalf >> 1;
            int lh = (ihalf & 1) * 32;
            int g  = (pxA & 1) * 4 + ks;          // pxB has same (px&1)
            bfrag hv, lv;
            split8(a0, a1, hv, lv);
            int rowA = (pxA >> 1) + lh;
            *(bfrag*)(hsfh + cur * 4096 + (g * 64 + (rowA ^ g)) * 8) = hv;
            *(bfrag*)(hsfl + cur * 4096 + (g * 64 + (rowA ^ g)) * 8) = lv;
            split8(b0, b1, hv, lv);
            int rowB = (pxB >> 1) + lh;
            *(bfrag*)(hsfh + cur * 4096 + (g * 64 + (rowB ^ g)) * 8) = hv;
            *(bfrag*)(hsfl + cur * 4096 + (g * 64 + (rowB ^ g)) * 8) = lv;
            __syncthreads();           // hsf[cur] ready
        }
        if (CONV && ht < 7){
            const float* hb2 = hb + (size_t)(ht + 1) * 32 * S * 64;
            a0 = *(const float4*)(hb2 + offA);
            a1 = *(const float4*)(hb2 + offA + 4);
            b0 = *(const float4*)(hb2 + offB);
            b1 = *(const float4*)(hb2 + offB + 4);
        }

        f32x16 acc = {0,0,0,0,0,0,0,0,0,0,0,0,0,0,0,0};

        // DCT matmul: A = DT rows ht*32.., B = register t2 fragments
        int hh0 = ht * 32;
        #pragma unroll
        for (int ks = 0; ks < 2; ks++){
            int aoff = (hh0 + (l & 31)) * KPB + ks * 16 + (l >> 5) * 8;
            bfrag ah = *(const bfrag*)(dth + aoff);
            bfrag al = *(const bfrag*)(dtl + aoff);
            acc = __builtin_amdgcn_mfma_f32_32x32x16_bf16(ah, t2h[ks], acc, 0, 0, 0);
            acc = __builtin_amdgcn_mfma_f32_32x32x16_bf16(ah, t2l[ks], acc, 0, 0, 0);
            acc = __builtin_amdgcn_mfma_f32_32x32x16_bf16(al, t2h[ks], acc, 0, 0, 0);
        }

        if (CONV){
            #pragma unroll
            for (int ks = 0; ks < 4; ks++){
                int g = wl * 4 + ks;
                int aoff = cur * 4096 + (g * 64 + (l ^ g)) * 8;
                bfrag ah = *(const bfrag*)(hsfh + aoff);
                bfrag al = *(const bfrag*)(hsfl + aoff);
                int boff = o * 64 + ks * 16 + (l >> 5) * 8;
                bfrag bh = *(const bfrag*)(pwh + boff);
                bfrag bl = *(const bfrag*)(pwl + boff);
                acc = __builtin_amdgcn_mfma_f32_32x32x16_bf16(ah, bh, acc, 0, 0, 0);
                acc = __builtin_amdgcn_mfma_f32_32x32x16_bf16(ah, bl, acc, 0, 0, 0);
                acc = __builtin_amdgcn_mfma_f32_32x32x16_bf16(al, bh, acc, 0, 0, 0);
            }
            float pbv = pb[o];
            #pragma unroll
            for (int r = 0; r < 16; r++){
                int row = (r & 3) + 8 * (r >> 2) + 4 * (l >> 5);
                int ei = cur * 4096 + (g_res * 64 + ((row + rowadd) ^ g_res)) * 8 + jres;
                float res = bf2f(hsfh[ei]) + bf2f(hsfl[ei]);
                size_t pix = ((size_t)b * S + ht * 32 + row) * S + wt * 2 + wl;
                h[pix * 64 + o] = res + gelu_f(acc[r] + pbv);
            }
            cur ^= 1;
        } else {
            if (o < 61){
                #pragma unroll
                for (int r = 0; r < 16; r++){
                    int row = (r & 3) + 8 * (r >> 2) + 4 * (l >> 5);
                    size_t pix = ((size_t)b * S + ht * 32 + row) * S + wt * 2 + wl;
                    h[pix * 64 + 3 + o] = gelu_f(acc[r]);
                }
            }
        }
    }
}

// MFMA k_mlp: P[64px][128j] = h[64px][64i] @ fc1[64i][128j]; out = gelu(P+b1)@fc2+b2.
__global__ __launch_bounds__(256, 4) void k_mlp(
        const float* __restrict__ h, const short* __restrict__ f1h,
        const short* __restrict__ f1l, const float* __restrict__ fc1b,
        const float* __restrict__ fc2w, const float* __restrict__ fc2b,
        float* __restrict__ out){
    __shared__ short ah_[2 * 4 * 64 * 8];   // [g=m*4+ks][row^g][j] hi, 8 KB
    __shared__ short al_[2 * 4 * 64 * 8];
    __shared__ float red[2 * 64 * 33];      // [pair][row][col], 16.9 KB
    size_t base = (size_t)blockIdx.x * 64;
    int t = threadIdx.x;
    const float* hrow = h + base * 64;
    // stage h (64px x 64i) as split-bf16 A-fragments (swizzled b128 writes)
    #pragma unroll
    for (int e2 = 0; e2 < 2; e2++){
        int e = t + e2 * 256;
        int px = e >> 3, ih = e & 7;
        float4 v0 = *(const float4*)(hrow + px * 64 + ih * 8);
        float4 v1 = *(const float4*)(hrow + px * 64 + ih * 8 + 4);
        bfrag hv, lv;
        split8(v0, v1, hv, lv);
        int g = (px >> 5) * 4 + (ih >> 1);
        int row = (px & 31) + (ih & 1) * 32;
        *(bfrag*)(ah_ + (g * 64 + (row ^ g)) * 8) = hv;
        *(bfrag*)(al_ + (g * 64 + (row ^ g)) * 8) = lv;
    }
    __syncthreads();
    int l = t & 63;
    int w = t >> 6;
    int m = w >> 1;
    int n0 = (w & 1) * 2;
    f32x16 acc0 = {0,0,0,0,0,0,0,0,0,0,0,0,0,0,0,0};
    f32x16 acc1 = {0,0,0,0,0,0,0,0,0,0,0,0,0,0,0,0};
    #pragma unroll
    for (int ks = 0; ks < 4; ks++){
        int g = m * 4 + ks;
        int aoff = (g * 64 + (l ^ g)) * 8;
        bfrag ah = *(const bfrag*)(ah_ + aoff);
        bfrag al = *(const bfrag*)(al_ + aoff);
        int b0off = ((n0 * 4 + ks) * 64 + l) * 8;
        int b1off = (((n0 + 1) * 4 + ks) * 64 + l) * 8;
        bfrag b0h = *(const bfrag*)(f1h + b0off);
        bfrag b0l = *(const bfrag*)(f1l + b0off);
        bfrag b1h = *(const bfrag*)(f1h + b1off);
        bfrag b1l = *(const bfrag*)(f1l + b1off);
        acc0 = __builtin_amdgcn_mfma_f32_32x32x16_bf16(ah, b0h, acc0, 0, 0, 0);
        acc0 = __builtin_amdgcn_mfma_f32_32x32x16_bf16(ah, b0l, acc0, 0, 0, 0);
        acc0 = __builtin_amdgcn_mfma_f32_32x32x16_bf16(al, b0h, acc0, 0, 0, 0);
        acc1 = __builtin_amdgcn_mfma_f32_32x32x16_bf16(ah, b1h, acc1, 0, 0, 0);
        acc1 = __builtin_amdgcn_mfma_f32_32x32x16_bf16(ah, b1l, acc1, 0, 0, 0);
        acc1 = __builtin_amdgcn_mfma_f32_32x32x16_bf16(al, b1h, acc1, 0, 0, 0);
    }
    int j0 = n0 * 32 + (l & 31), j1 = j0 + 32;
    float b10 = fc1b[j0], b11 = fc1b[j1];
    float f20 = fc2w[j0], f21 = fc2w[j1];
    float* rb = red + (w & 1) * 64 * 33;
    #pragma unroll
    for (int r = 0; r < 16; r++){
        int row = (r & 3) + 8 * (r >> 2) + 4 * (l >> 5);
        rb[(m * 32 + row) * 33 + (l & 31)] =
            gelu_f(acc0[r] + b10) * f20 + gelu_f(acc1[r] + b11) * f21;
    }
    __syncthreads();
    if (t < 64){
        float s = fc2b[0];
        #pragma unroll
        for (int c = 0; c < 32; c++)
            s += red[t * 33 + c] + red[(64 + t) * 33 + c];
        out[base + t] = s;
    }
}

extern "C" void kernel_launch(void* const* d_in, const int* in_sizes, int n_in,
                              void* d_out, int out_size, void* d_ws, size_t ws_size,
                              hipStream_t stream) {
    const float* x    = (const float*)d_in[0];
    const float* wl   = (const float*)d_in[1];
    const float* wc[4] = {(const float*)d_in[2], (const float*)d_in[3],
                          (const float*)d_in[4], (const float*)d_in[5]};
    const float* pw[4] = {(const float*)d_in[6], (const float*)d_in[8],
                          (const float*)d_in[10], (const float*)d_in[12]};
    const float* pb[4] = {(const float*)d_in[7], (const float*)d_in[9],
                          (const float*)d_in[11], (const float*)d_in[13]};
    const float* fc1w = (const float*)d_in[14];
    const float* fc1b = (const float*)d_in[15];
    const float* fc2w = (const float*)d_in[16];
    const float* fc2b = (const float*)d_in[17];
    float* out = (float*)d_out;

    char* ws = (char*)d_ws;
    size_t off = 0;
    float* dt   = (float*)(ws + off); off += (size_t)S * KPAD * 4;              // 36,864
    short* dth  = (short*)(ws + off); off += (size_t)S * KPB * 2;               // 20,480
    short* dtl  = (short*)(ws + off); off += (size_t)S * KPB * 2;               // 20,480
    short* pwh  = (short*)(ws + off); off += (size_t)4 * 4096 * 2;              // 32,768
    short* pwl  = (short*)(ws + off); off += (size_t)4 * 4096 * 2;              // 32,768
    short* f1h  = (short*)(ws + off); off += (size_t)8192 * 2;                  // 16,384
    short* f1l  = (short*)(ws + off); off += (size_t)8192 * 2;                  // 16,384
    float* h    = (float*)(ws + off); off += (size_t)BB * S * S * W64 * 4;      // 134,217,728
    float* tmp1 = (float*)(ws + off); off += (size_t)2 * BB * PP * S * W64 * 4; // 35,651,584
    float* bp   = (float*)(ws + off); off += (size_t)BB * PP * PP * W64 * 4;    // 2,367,488
    float* xp   = (float*)(ws + off); off += (size_t)576 * 1024 * 8 * 4;        // 18,874,368
    float* t2   = (float*)(ws + off); off += (size_t)BB * 32 * S * W64 * 4;     // 16,777,216
    // part (8 slices x 2.1MB = 16.8MB) ALIASES tmp1 (35.6MB): in the serialized
    // stream, tmp1 is fully consumed by k_fwd2 before k_om writes part, and
    // part is consumed by k_inv1 before the next blk's k_fwd1 rewrites tmp1.
    float* part = tmp1;

    k_init_dt<<<(S * KPB + 255) / 256, 256, 0, stream>>>(dt, dth, dtl);
    for (int i = 0; i < 4; i++)
        k_prep_pw<<<16, 256, 0, stream>>>(pw[i], pwh + i * 4096, pwl + i * 4096);
    k_prep_fc1<<<32, 256, 0, stream>>>(fc1w, f1h, f1l);
    k_copy_x<<<(BB * S * S * CIN + 255) / 256, 256, 0, stream>>>(x, h);

    // ---- block 0: h[:, :, :, 3:] = gelu(pseudo_spectra(x, wl, 61)) ----
    k_fwd1<3><<<dim3(3, BB), 256, 0, stream>>>(x, tmp1, dt);
    k_fwd2_3<<<dim3(1, BB), 256, 0, stream>>>(tmp1, bp, dt);
    k_xp_gather<3, 3><<<dim3(32, 1), 256, 0, stream>>>(bp, xp);
    k_om<27, 61, 3><<<768, 256, 0, stream>>>(xp, wl, part);
    k_inv1<61, 3><<<dim3(8, 32, BB), 256, 0, stream>>>(part, t2, dt);
    k_fused<false><<<dim3(128, BB), 256, 0, stream>>>(
        t2, h, nullptr, nullptr, nullptr, dth, dtl);

    // ---- blocks 1..4 ----
    for (int blk = 0; blk < 4; blk++){
        k_fwd1_64s<<<dim3(64, 2, BB), 256, 0, stream>>>(h, tmp1, dt);
        k_fwd2_64<<<dim3(PP, BB), 256, 0, stream>>>(tmp1, bp, dt);
        k_xp_gather<64, 16><<<dim3(32, 4), 256, 0, stream>>>(bp, xp);
        k_om<576, 64, 8><<<2048, 256, 0, stream>>>(xp, wc[blk], part);
        k_inv1<64, 8><<<dim3(8, 32, BB), 256, 0, stream>>>(part, t2, dt);
        k_fused<true><<<dim3(128, BB), 256, 0, stream>>>(
            t2, h, pwh + blk * 4096, pwl + blk * 4096, pb[blk], dth, dtl);
    }

    // ---- final MLP (T_fwd(T_inv2(.)) is identity for the orthonormal DCT) ----
    k_mlp<<<dim3(BB * S * S / 64), 256, 0, stream>>>(h, f1h, f1l, fc1b, fc2w, fc2b, out);
}

// Round 22
// 1142.378 us; speedup vs baseline: 1.0581x; 1.0581x over previous
//
#include <hip/hip_runtime.h>
#include <math.h>

#define BB 8
#define S 256
#define CIN 3
#define W64 64
#define MODES 32
#define PP 34     // MODES + BW - 1
#define KPAD 36   // padded leading dim for f32 Dt
#define KPB 40    // padded leading dim for bf16 Dt tables (16B-aligned frag loads)

typedef __attribute__((ext_vector_type(8))) short bfrag;    // 8 bf16 raw bits
typedef __attribute__((ext_vector_type(16))) float f32x16;

// fast erf-based gelu: A&S 7.1.26, |erf err| <= 1.5e-7 (libm erff is ~40 insts)
__device__ __forceinline__ float gelu_f(float x){
    float z = fabsf(x) * 0.70710678118654752f;
    float t = 1.0f / (1.0f + 0.3275911f * z);
    float p = ((((1.061405429f * t - 1.453152027f) * t) + 1.421413741f) * t
               - 0.284496736f) * t + 0.254829592f;
    float e = __expf(-z * z);
    float erf = 1.0f - p * t * e;
    erf = copysignf(erf, x);
    return 0.5f * x * (1.0f + erf);
}

// accurate split (round-to-nearest hi): used in one-time weight/DT prep
__device__ __forceinline__ void split_bf(float x, short &hi, short &lo){
    unsigned u = __float_as_uint(x);
    unsigned r = u + 0x7FFFu + ((u >> 16) & 1u);
    hi = (short)(r >> 16);
    float hf = __uint_as_float(r & 0xFFFF0000u);
    float l = x - hf;
    unsigned v = __float_as_uint(l);
    unsigned s2 = v + 0x7FFFu + ((v >> 16) & 1u);
    lo = (short)(s2 >> 16);
}

// fast split (truncated hi): per-dispatch hot staging paths. err <= 2^-15 |x|.
__device__ __forceinline__ void split_bf_fast(float x, short &hi, short &lo){
    unsigned u = __float_as_uint(x);
    hi = (short)(u >> 16);
    float hf = __uint_as_float(u & 0xFFFF0000u);
    float l = x - hf;
    unsigned v = __float_as_uint(l);
    unsigned s2 = v + 0x7FFFu + ((v >> 16) & 1u);
    lo = (short)(s2 >> 16);
}

// split 8 floats (two float4) into hi/lo bfrags (fast variant)
__device__ __forceinline__ void split8(float4 a, float4 b, bfrag &hv, bfrag &lv){
    short hi, lo;
    split_bf_fast(a.x, hi, lo); hv[0] = hi; lv[0] = lo;
    split_bf_fast(a.y, hi, lo); hv[1] = hi; lv[1] = lo;
    split_bf_fast(a.z, hi, lo); hv[2] = hi; lv[2] = lo;
    split_bf_fast(a.w, hi, lo); hv[3] = hi; lv[3] = lo;
    split_bf_fast(b.x, hi, lo); hv[4] = hi; lv[4] = lo;
    split_bf_fast(b.y, hi, lo); hv[5] = hi; lv[5] = lo;
    split_bf_fast(b.z, hi, lo); hv[6] = hi; lv[6] = lo;
    split_bf_fast(b.w, hi, lo); hv[7] = hi; lv[7] = lo;
}

__device__ __forceinline__ float bf2f(short s){
    return __uint_as_float(((unsigned)(unsigned short)s) << 16);
}

// dt[h*36+k] = DCT[k,h] f32; dth/dtl[h*40+k] = bf16 hi/lo split
__global__ void k_init_dt(float* __restrict__ dt, short* __restrict__ dth,
                          short* __restrict__ dtl){
    int tid = blockIdx.x * 256 + threadIdx.x;
    if (tid >= S * KPB) return;
    int h = tid / KPB, k = tid % KPB;
    double v = 0.0;
    if (k < PP) {
        v = sqrt(2.0 / (double)S) * cos(3.14159265358979323846 * (h + 0.5) * k / (double)S);
        if (k == 0) v *= 0.70710678118654752440;
    }
    float f = (float)v;
    if (k < KPAD) dt[h * KPAD + k] = f;
    short hi, lo; split_bf(f, hi, lo);
    dth[tid] = hi; dtl[tid] = lo;
}

// split a 64x64 conv weight into bf16 hi/lo (layout preserved: pw[o][i])
__global__ void k_prep_pw(const float* __restrict__ pw, short* __restrict__ pwh,
                          short* __restrict__ pwl){
    int e = blockIdx.x * 256 + threadIdx.x;
    if (e >= 4096) return;
    short hi, lo; split_bf(pw[e], hi, lo);
    pwh[e] = hi; pwl[e] = lo;
}

// split fc1 (64 i x 128 j) into B-fragment-ordered hi/lo
__global__ void k_prep_fc1(const float* __restrict__ fc1w, short* __restrict__ f1h,
                           short* __restrict__ f1l){
    int e = blockIdx.x * 256 + threadIdx.x;
    if (e >= 8192) return;
    int i = e >> 7, j = e & 127;
    int n = j >> 5, ks = i >> 4;
    int l = (j & 31) + (((i & 15) >= 8) ? 32 : 0);
    int jr = i & 7;
    int idx = ((n * 4 + ks) * 64 + l) * 8 + jr;
    short hi, lo; split_bf(fc1w[e], hi, lo);
    f1h[idx] = hi; f1l[idx] = lo;
}

// x (B,S,S,3) -> h channels 0..2 (channels-last h: (B,S,S,64))
__global__ void k_copy_x(const float* __restrict__ x, float* __restrict__ h){
    int e = blockIdx.x * 256 + threadIdx.x;
    if (e >= BB * S * S * CIN) return;
    int px = e / CIN, c = e % CIN;
    h[(size_t)px * W64 + c] = x[e];
}

// tmp1[b][k][w][c] = sum_h Dt[h][k] * src[b][h][w][c]   (C=3, block0 path)
template<int C>
__global__ void k_fwd1(const float* __restrict__ src, float* __restrict__ tmp1,
                       const float* __restrict__ dt){
    int b = blockIdx.y;
    int idx = blockIdx.x * 256 + threadIdx.x;   // flat (w, c)
    if (idx >= S * C) return;
    float acc[PP];
    #pragma unroll
    for (int k = 0; k < PP; k++) acc[k] = 0.f;
    const float* sp = src + (size_t)b * S * S * C + idx;
    for (int hh = 0; hh < S; hh++){
        float v = sp[(size_t)hh * S * C];
        const float* dr = dt + hh * KPAD;
        #pragma unroll
        for (int k = 0; k < PP; k++) acc[k] = fmaf(dr[k], v, acc[k]);
    }
    float* op = tmp1 + (size_t)b * PP * S * C + idx;
    #pragma unroll
    for (int k = 0; k < PP; k++) op[(size_t)k * S * C] = acc[k];
}

// C=64, h-split: half hf reduces h in [hf*128, hf*128+128) -> tmp1 + hf*TM1.
__global__ void k_fwd1_64s(const float* __restrict__ src, float* __restrict__ tmp1,
                           const float* __restrict__ dt){
    const int C = 64;
    const size_t TM1 = (size_t)BB * PP * S * C;
    int b = blockIdx.z, hf = blockIdx.y;
    int idx = blockIdx.x * 256 + threadIdx.x;   // flat (w, c)
    float acc[PP];
    #pragma unroll
    for (int k = 0; k < PP; k++) acc[k] = 0.f;
    const float* sp = src + (size_t)b * S * S * C + (size_t)hf * 128 * S * C + idx;
    for (int hh = 0; hh < 128; hh++){
        float v = sp[(size_t)hh * S * C];
        const float* dr = dt + (hf * 128 + hh) * KPAD;
        #pragma unroll
        for (int k = 0; k < PP; k++) acc[k] = fmaf(dr[k], v, acc[k]);
    }
    float* op = tmp1 + (size_t)hf * TM1 + (size_t)b * PP * S * C + idx;
    #pragma unroll
    for (int k = 0; k < PP; k++) op[(size_t)k * S * C] = acc[k];
}

// bp[b][k][l][c] = sum_w Dt[w][l] * tmp1[b][k][w][c]   (C=3 path, tiny)
__global__ void k_fwd2_3(const float* __restrict__ tmp1, float* __restrict__ bp,
                         const float* __restrict__ dt){
    const int C = 3;
    int b = blockIdx.y;
    int idx = blockIdx.x * 256 + threadIdx.x;   // flat (k, c)
    if (idx >= PP * C) return;
    int k = idx / C, c = idx % C;
    float acc[PP];
    #pragma unroll
    for (int l = 0; l < PP; l++) acc[l] = 0.f;
    const float* sp = tmp1 + ((size_t)b * PP + k) * S * C + c;
    for (int w = 0; w < S; w++){
        float v = sp[(size_t)w * C];
        const float* dr = dt + w * KPAD;
        #pragma unroll
        for (int l = 0; l < PP; l++) acc[l] = fmaf(dr[l], v, acc[l]);
    }
    float* op = bp + ((size_t)b * PP + k) * PP * C + c;
    #pragma unroll
    for (int l = 0; l < PP; l++) op[(size_t)l * C] = acc[l];
}

// C=64: block = (k, b), 4 waves each own a 64-wide w-segment, LDS reduce.
// Sums the two tmp1 h-halves while streaming.
__global__ __launch_bounds__(256, 4) void k_fwd2_64(
        const float* __restrict__ tmp1, float* __restrict__ bp,
        const float* __restrict__ dt){
    const int C = 64;
    const size_t TM1 = (size_t)BB * PP * S * C;
    __shared__ float red[4 * PP * 66];   // 35.9 KB
    int k = blockIdx.x, b = blockIdx.y;
    int t = threadIdx.x;
    int c = t & 63;
    int ws = __builtin_amdgcn_readfirstlane(t >> 6);
    float acc[PP];
    #pragma unroll
    for (int l = 0; l < PP; l++) acc[l] = 0.f;
    const float* sp = tmp1 + ((size_t)b * PP + k) * S * C + c;
    for (int w = ws * 64; w < ws * 64 + 64; w++){
        float v = sp[(size_t)w * C] + sp[TM1 + (size_t)w * C];
        const float* dr = dt + w * KPAD;
        #pragma unroll
        for (int l = 0; l < PP; l++) acc[l] = fmaf(dr[l], v, acc[l]);
    }
    #pragma unroll
    for (int l = 0; l < PP; l++) red[(ws * PP + l) * 66 + c] = acc[l];
    __syncthreads();
    float* op = bp + ((size_t)b * PP + k) * PP * C;
    for (int e = t; e < PP * C; e += 256){
        int l = e >> 6, cc = e & 63;
        op[e] = red[(0 * PP + l) * 66 + cc] + red[(1 * PP + l) * 66 + cc]
              + red[(2 * PP + l) * 66 + cc] + red[(3 * PP + l) * 66 + cc];
    }
}

// xp[i][kl][b] = bp[b][k+i_][l+j_][c],  i = c*9 + i_*3 + j_, kl = k*32 + l
template<int C, int CC>
__global__ void k_xp_gather(const float* __restrict__ bp, float* __restrict__ xp){
    __shared__ float lds[8 * 3 * PP * (CC + 1)];
    int k  = blockIdx.x;           // 0..31
    int c0 = blockIdx.y * CC;
    int t  = threadIdx.x;
    const int TOT = 8 * 3 * PP * CC;
    for (int e = t; e < TOT; e += 256){
        int b   = e / (3 * PP * CC);
        int r   = e % (3 * PP * CC);
        int row = r / (PP * CC);
        int r2  = r % (PP * CC);
        int l   = r2 / CC;
        int c   = r2 % CC;
        lds[((b * 3 + row) * PP + l) * (CC + 1) + c] =
            bp[(((size_t)b * PP + (k + row)) * PP + l) * C + c0 + c];
    }
    __syncthreads();
    int l = t >> 3;   // 0..31
    int b = t & 7;
    for (int c = 0; c < CC; c++){
        #pragma unroll
        for (int ij = 0; ij < 9; ij++){
            int i_ = ij / 3, j_ = ij % 3;
            int i  = (c0 + c) * 9 + ij;
            float v = lds[((b * 3 + i_) * PP + (l + j_)) * (CC + 1) + c];
            xp[((size_t)i * 1024 + k * 32 + l) * 8 + b] = v;
        }
    }
}

// part[ns][b][o][kl] = sum_{i in slice ns} xp[i][kl][b] * w[i][o][kl]
template<int ITOT, int O>
__global__ void k_om(const float* __restrict__ xp, const float* __restrict__ w,
                     float* __restrict__ part){
    int bx  = blockIdx.x;
    int klt = bx & 31;
    int ot  = (bx >> 5) & 7;
    int ns  = bx >> 8;              // 0..2
    const int ILEN = ITOT / 3;
    int t  = threadIdx.x;
    int kl = klt * 32 + (t & 31);
    int o  = ot * 8 + (t >> 5);
    if (o >= O) return;
    float a0=0,a1=0,a2=0,a3=0,a4=0,a5=0,a6=0,a7=0;
    const float* xpp = xp + ((size_t)(ns * ILEN) * 1024 + kl) * 8;
    const float* wp  = w + ((size_t)(ns * ILEN) * O + o) * 1024 + kl;
    #pragma unroll 4
    for (int i = 0; i < ILEN; i++){
        float4 xa = *(const float4*)(xpp + (size_t)i * 8192);
        float4 xb = *(const float4*)(xpp + (size_t)i * 8192 + 4);
        float wv  = wp[(size_t)i * O * 1024];
        a0 = fmaf(xa.x, wv, a0); a1 = fmaf(xa.y, wv, a1);
        a2 = fmaf(xa.z, wv, a2); a3 = fmaf(xa.w, wv, a3);
        a4 = fmaf(xb.x, wv, a4); a5 = fmaf(xb.y, wv, a5);
        a6 = fmaf(xb.z, wv, a6); a7 = fmaf(xb.w, wv, a7);
    }
    float* pp = part + (size_t)ns * 8 * 64 * 1024;
    pp[((size_t)0 * 64 + o) * 1024 + kl] = a0;
    pp[((size_t)1 * 64 + o) * 1024 + kl] = a1;
    pp[((size_t)2 * 64 + o) * 1024 + kl] = a2;
    pp[((size_t)3 * 64 + o) * 1024 + kl] = a3;
    pp[((size_t)4 * 64 + o) * 1024 + kl] = a4;
    pp[((size_t)5 * 64 + o) * 1024 + kl] = a5;
    pp[((size_t)6 * 64 + o) * 1024 + kl] = a6;
    pp[((size_t)7 * 64 + o) * 1024 + kl] = a7;
}

// t2[b][k][w][o] = sum_l Dt[w][l] * om[b][o][k*32+l]; om = sum of 3 part slices
template<int O>
__global__ void k_inv1(const float* __restrict__ part, float* __restrict__ t2,
                       const float* __restrict__ dt){
    __shared__ float oms[32 * 65];
    const int N = 8 * 64 * 1024;
    int wc = blockIdx.x, k = blockIdx.y, b = blockIdx.z;
    int t = threadIdx.x;
    for (int e = t; e < 2048; e += 256){
        int o_ = e >> 5, l = e & 31;
        int idx = ((b * 64 + o_) << 10) + k * 32 + l;
        oms[l * 65 + o_] = part[idx] + part[N + idx] + part[2 * N + idx];
    }
    __syncthreads();
    int o  = t & 63;
    int wg = __builtin_amdgcn_readfirstlane(t >> 6);
    int wbase = wc * 32 + wg * 8;
    float acc[8];
    #pragma unroll
    for (int wj = 0; wj < 8; wj++) acc[wj] = 0.f;
    for (int l = 0; l < 32; l++){
        float ov = oms[l * 65 + o];
        #pragma unroll
        for (int wj = 0; wj < 8; wj++)
            acc[wj] = fmaf(dt[(wbase + wj) * KPAD + l], ov, acc[wj]);
    }
    if (o < O){
        #pragma unroll
        for (int wj = 0; wj < 8; wj++)
            t2[(((size_t)b * 32 + k) * S + wbase + wj) * 64 + o] = acc[wj];
    }
}

// MFMA k_fused v5 (R16 structure, best measured): ht-loop, t2 B-frags in
// registers (ht-invariant), hsf double-buffered, one barrier per ht,
// residual reconstructed from hsf hi/lo pair. LDS 32KB.
template<bool CONV>
__global__ __launch_bounds__(256, 4) void k_fused(
        const float* __restrict__ t2, float* __restrict__ h,
        const short* __restrict__ pwh, const short* __restrict__ pwl,
        const float* __restrict__ pb,
        const short* __restrict__ dth, const short* __restrict__ dtl){
    __shared__ short hsfh[CONV ? 2 * 8 * 64 * 8 : 1];      // [buf][g][row^g][j]
    __shared__ short hsfl[CONV ? 2 * 8 * 64 * 8 : 1];
    int wt = blockIdx.x, b = blockIdx.y;
    int t = threadIdx.x;
    int l = t & 63;
    int n = t >> 6;
    int oh = n & 1, wl = n >> 1;
    int o = oh * 32 + (l & 31);

    // ---- t2 B-fragments direct to regs (ht-invariant)
    bfrag t2h[2], t2l[2];
    {
        const float* tp = t2 + ((size_t)(b * 32 + (l >> 5) * 8) * S + wt * 2 + wl) * 64 + o;
        #pragma unroll
        for (int ks = 0; ks < 2; ks++){
            #pragma unroll
            for (int j = 0; j < 8; j++){
                short hi, lo;
                split_bf_fast(tp[(size_t)(ks * 16 + j) * S * 64], hi, lo);
                t2h[ks][j] = hi; t2l[ks][j] = lo;
            }
        }
    }

    // residual-reconstruct constants (fixed per thread)
    int g_res = wl * 4 + (o >> 4);
    int jres  = o & 7;
    int rowadd = ((o & 15) >= 8) ? 32 : 0;

    // prefetch geometry: task A = (pxA, ihalf), task B = (pxA+32, ihalf)
    int ihalf = t & 7;
    int pxA = t >> 3;          // 0..31
    int pxB = pxA + 32;        // 32..63
    const float* hb = h + ((size_t)b * S * S + (size_t)wt * 2) * 64;
    size_t offA = ((size_t)(pxA >> 1) * S + (pxA & 1)) * 64 + ihalf * 8;
    size_t offB = ((size_t)(pxB >> 1) * S + (pxB & 1)) * 64 + ihalf * 8;
    float4 a0, a1, b0, b1;
    if (CONV){
        a0 = *(const float4*)(hb + offA);
        a1 = *(const float4*)(hb + offA + 4);
        b0 = *(const float4*)(hb + offB);
        b1 = *(const float4*)(hb + offB + 4);
    }

    int cur = 0;
    for (int ht = 0; ht < 8; ht++){
        if (CONV){
            // write hsf[cur] from prefetched regs (swizzled b128)
            int ks = ihalf >> 1;
            int lh = (ihalf & 1) * 32;
            int g  = (pxA & 1) * 4 + ks;          // pxB has same (px&1)
            bfrag hv, lv;
            split8(a0, a1, hv, lv);
            int rowA = (pxA >> 1) + lh;
            *(bfrag*)(hsfh + cur * 4096 + (g * 64 + (rowA ^ g)) * 8) = hv;
            *(bfrag*)(hsfl + cur * 4096 + (g * 64 + (rowA ^ g)) * 8) = lv;
            split8(b0, b1, hv, lv);
            int rowB = (pxB >> 1) + lh;
            *(bfrag*)(hsfh + cur * 4096 + (g * 64 + (rowB ^ g)) * 8) = hv;
            *(bfrag*)(hsfl + cur * 4096 + (g * 64 + (rowB ^ g)) * 8) = lv;
            __syncthreads();           // hsf[cur] ready
        }
        if (CONV && ht < 7){
            const float* hb2 = hb + (size_t)(ht + 1) * 32 * S * 64;
            a0 = *(const float4*)(hb2 + offA);
            a1 = *(const float4*)(hb2 + offA + 4);
            b0 = *(const float4*)(hb2 + offB);
            b1 = *(const float4*)(hb2 + offB + 4);
        }

        f32x16 acc = {0,0,0,0,0,0,0,0,0,0,0,0,0,0,0,0};

        // DCT matmul: A = DT rows ht*32.., B = register t2 fragments
        int hh0 = ht * 32;
        #pragma unroll
        for (int ks = 0; ks < 2; ks++){
            int aoff = (hh0 + (l & 31)) * KPB + ks * 16 + (l >> 5) * 8;
            bfrag ah = *(const bfrag*)(dth + aoff);
            bfrag al = *(const bfrag*)(dtl + aoff);
            acc = __builtin_amdgcn_mfma_f32_32x32x16_bf16(ah, t2h[ks], acc, 0, 0, 0);
            acc = __builtin_amdgcn_mfma_f32_32x32x16_bf16(ah, t2l[ks], acc, 0, 0, 0);
            acc = __builtin_amdgcn_mfma_f32_32x32x16_bf16(al, t2h[ks], acc, 0, 0, 0);
        }

        if (CONV){
            #pragma unroll
            for (int ks = 0; ks < 4; ks++){
                int g = wl * 4 + ks;
                int aoff = cur * 4096 + (g * 64 + (l ^ g)) * 8;
                bfrag ah = *(const bfrag*)(hsfh + aoff);
                bfrag al = *(const bfrag*)(hsfl + aoff);
                int boff = o * 64 + ks * 16 + (l >> 5) * 8;
                bfrag bh = *(const bfrag*)(pwh + boff);
                bfrag bl = *(const bfrag*)(pwl + boff);
                acc = __builtin_amdgcn_mfma_f32_32x32x16_bf16(ah, bh, acc, 0, 0, 0);
                acc = __builtin_amdgcn_mfma_f32_32x32x16_bf16(ah, bl, acc, 0, 0, 0);
                acc = __builtin_amdgcn_mfma_f32_32x32x16_bf16(al, bh, acc, 0, 0, 0);
            }
            float pbv = pb[o];
            #pragma unroll
            for (int r = 0; r < 16; r++){
                int row = (r & 3) + 8 * (r >> 2) + 4 * (l >> 5);
                int ei = cur * 4096 + (g_res * 64 + ((row + rowadd) ^ g_res)) * 8 + jres;
                float res = bf2f(hsfh[ei]) + bf2f(hsfl[ei]);
                size_t pix = ((size_t)b * S + ht * 32 + row) * S + wt * 2 + wl;
                h[pix * 64 + o] = res + gelu_f(acc[r] + pbv);
            }
            cur ^= 1;
        } else {
            if (o < 61){
                #pragma unroll
                for (int r = 0; r < 16; r++){
                    int row = (r & 3) + 8 * (r >> 2) + 4 * (l >> 5);
                    size_t pix = ((size_t)b * S + ht * 32 + row) * S + wt * 2 + wl;
                    h[pix * 64 + 3 + o] = gelu_f(acc[r]);
                }
            }
        }
    }
}

// MFMA k_mlp: P[64px][128j] = h[64px][64i] @ fc1[64i][128j]; out = gelu(P+b1)@fc2+b2.
__global__ __launch_bounds__(256, 4) void k_mlp(
        const float* __restrict__ h, const short* __restrict__ f1h,
        const short* __restrict__ f1l, const float* __restrict__ fc1b,
        const float* __restrict__ fc2w, const float* __restrict__ fc2b,
        float* __restrict__ out){
    __shared__ short ah_[2 * 4 * 64 * 8];   // [g=m*4+ks][row^g][j] hi, 8 KB
    __shared__ short al_[2 * 4 * 64 * 8];
    __shared__ float red[2 * 64 * 33];      // [pair][row][col], 16.9 KB
    size_t base = (size_t)blockIdx.x * 64;
    int t = threadIdx.x;
    const float* hrow = h + base * 64;
    // stage h (64px x 64i) as split-bf16 A-fragments (swizzled b128 writes)
    #pragma unroll
    for (int e2 = 0; e2 < 2; e2++){
        int e = t + e2 * 256;
        int px = e >> 3, ih = e & 7;
        float4 v0 = *(const float4*)(hrow + px * 64 + ih * 8);
        float4 v1 = *(const float4*)(hrow + px * 64 + ih * 8 + 4);
        bfrag hv, lv;
        split8(v0, v1, hv, lv);
        int g = (px >> 5) * 4 + (ih >> 1);
        int row = (px & 31) + (ih & 1) * 32;
        *(bfrag*)(ah_ + (g * 64 + (row ^ g)) * 8) = hv;
        *(bfrag*)(al_ + (g * 64 + (row ^ g)) * 8) = lv;
    }
    __syncthreads();
    int l = t & 63;
    int w = t >> 6;
    int m = w >> 1;
    int n0 = (w & 1) * 2;
    f32x16 acc0 = {0,0,0,0,0,0,0,0,0,0,0,0,0,0,0,0};
    f32x16 acc1 = {0,0,0,0,0,0,0,0,0,0,0,0,0,0,0,0};
    #pragma unroll
    for (int ks = 0; ks < 4; ks++){
        int g = m * 4 + ks;
        int aoff = (g * 64 + (l ^ g)) * 8;
        bfrag ah = *(const bfrag*)(ah_ + aoff);
        bfrag al = *(const bfrag*)(al_ + aoff);
        int b0off = ((n0 * 4 + ks) * 64 + l) * 8;
        int b1off = (((n0 + 1) * 4 + ks) * 64 + l) * 8;
        bfrag b0h = *(const bfrag*)(f1h + b0off);
        bfrag b0l = *(const bfrag*)(f1l + b0off);
        bfrag b1h = *(const bfrag*)(f1h + b1off);
        bfrag b1l = *(const bfrag*)(f1l + b1off);
        acc0 = __builtin_amdgcn_mfma_f32_32x32x16_bf16(ah, b0h, acc0, 0, 0, 0);
        acc0 = __builtin_amdgcn_mfma_f32_32x32x16_bf16(ah, b0l, acc0, 0, 0, 0);
        acc0 = __builtin_amdgcn_mfma_f32_32x32x16_bf16(al, b0h, acc0, 0, 0, 0);
        acc1 = __builtin_amdgcn_mfma_f32_32x32x16_bf16(ah, b1h, acc1, 0, 0, 0);
        acc1 = __builtin_amdgcn_mfma_f32_32x32x16_bf16(ah, b1l, acc1, 0, 0, 0);
        acc1 = __builtin_amdgcn_mfma_f32_32x32x16_bf16(al, b1h, acc1, 0, 0, 0);
    }
    int j0 = n0 * 32 + (l & 31), j1 = j0 + 32;
    float b10 = fc1b[j0], b11 = fc1b[j1];
    float f20 = fc2w[j0], f21 = fc2w[j1];
    float* rb = red + (w & 1) * 64 * 33;
    #pragma unroll
    for (int r = 0; r < 16; r++){
        int row = (r & 3) + 8 * (r >> 2) + 4 * (l >> 5);
        rb[(m * 32 + row) * 33 + (l & 31)] =
            gelu_f(acc0[r] + b10) * f20 + gelu_f(acc1[r] + b11) * f21;
    }
    __syncthreads();
    if (t < 64){
        float s = fc2b[0];
        #pragma unroll
        for (int c = 0; c < 32; c++)
            s += red[t * 33 + c] + red[(64 + t) * 33 + c];
        out[base + t] = s;
    }
}

extern "C" void kernel_launch(void* const* d_in, const int* in_sizes, int n_in,
                              void* d_out, int out_size, void* d_ws, size_t ws_size,
                              hipStream_t stream) {
    const float* x    = (const float*)d_in[0];
    const float* wl   = (const float*)d_in[1];
    const float* wc[4] = {(const float*)d_in[2], (const float*)d_in[3],
                          (const float*)d_in[4], (const float*)d_in[5]};
    const float* pw[4] = {(const float*)d_in[6], (const float*)d_in[8],
                          (const float*)d_in[10], (const float*)d_in[12]};
    const float* pb[4] = {(const float*)d_in[7], (const float*)d_in[9],
                          (const float*)d_in[11], (const float*)d_in[13]};
    const float* fc1w = (const float*)d_in[14];
    const float* fc1b = (const float*)d_in[15];
    const float* fc2w = (const float*)d_in[16];
    const float* fc2b = (const float*)d_in[17];
    float* out = (float*)d_out;

    char* ws = (char*)d_ws;
    size_t off = 0;
    float* dt   = (float*)(ws + off); off += (size_t)S * KPAD * 4;              // 36,864
    short* dth  = (short*)(ws + off); off += (size_t)S * KPB * 2;               // 20,480
    short* dtl  = (short*)(ws + off); off += (size_t)S * KPB * 2;               // 20,480
    short* pwh  = (short*)(ws + off); off += (size_t)4 * 4096 * 2;              // 32,768
    short* pwl  = (short*)(ws + off); off += (size_t)4 * 4096 * 2;              // 32,768
    short* f1h  = (short*)(ws + off); off += (size_t)8192 * 2;                  // 16,384
    short* f1l  = (short*)(ws + off); off += (size_t)8192 * 2;                  // 16,384
    float* h    = (float*)(ws + off); off += (size_t)BB * S * S * W64 * 4;      // 134,217,728
    float* tmp1 = (float*)(ws + off); off += (size_t)2 * BB * PP * S * W64 * 4; // 35,651,584
    float* bp   = (float*)(ws + off); off += (size_t)BB * PP * PP * W64 * 4;    // 2,367,488
    float* xp   = (float*)(ws + off); off += (size_t)576 * 1024 * 8 * 4;        // 18,874,368
    float* part = (float*)(ws + off); off += (size_t)3 * 8 * 64 * 1024 * 4;     // 6,291,456
    float* t2   = (float*)(ws + off); off += (size_t)BB * 32 * S * W64 * 4;     // 16,777,216

    k_init_dt<<<(S * KPB + 255) / 256, 256, 0, stream>>>(dt, dth, dtl);
    for (int i = 0; i < 4; i++)
        k_prep_pw<<<16, 256, 0, stream>>>(pw[i], pwh + i * 4096, pwl + i * 4096);
    k_prep_fc1<<<32, 256, 0, stream>>>(fc1w, f1h, f1l);
    k_copy_x<<<(BB * S * S * CIN + 255) / 256, 256, 0, stream>>>(x, h);

    // ---- block 0: h[:, :, :, 3:] = gelu(pseudo_spectra(x, wl, 61)) ----
    k_fwd1<3><<<dim3(3, BB), 256, 0, stream>>>(x, tmp1, dt);
    k_fwd2_3<<<dim3(1, BB), 256, 0, stream>>>(tmp1, bp, dt);
    k_xp_gather<3, 3><<<dim3(32, 1), 256, 0, stream>>>(bp, xp);
    k_om<27, 61><<<768, 256, 0, stream>>>(xp, wl, part);
    k_inv1<61><<<dim3(8, 32, BB), 256, 0, stream>>>(part, t2, dt);
    k_fused<false><<<dim3(128, BB), 256, 0, stream>>>(
        t2, h, nullptr, nullptr, nullptr, dth, dtl);

    // ---- blocks 1..4 ----
    for (int blk = 0; blk < 4; blk++){
        k_fwd1_64s<<<dim3(64, 2, BB), 256, 0, stream>>>(h, tmp1, dt);
        k_fwd2_64<<<dim3(PP, BB), 256, 0, stream>>>(tmp1, bp, dt);
        k_xp_gather<64, 16><<<dim3(32, 4), 256, 0, stream>>>(bp, xp);
        k_om<576, 64><<<768, 256, 0, stream>>>(xp, wc[blk], part);
        k_inv1<64><<<dim3(8, 32, BB), 256, 0, stream>>>(part, t2, dt);
        k_fused<true><<<dim3(128, BB), 256, 0, stream>>>(
            t2, h, pwh + blk * 4096, pwl + blk * 4096, pb[blk], dth, dtl);
    }

    // ---- final MLP (T_fwd(T_inv2(.)) is identity for the orthonormal DCT) ----
    k_mlp<<<dim3(BB * S * S / 64), 256, 0, stream>>>(h, f1h, f1l, fc1b, fc2w, fc2b, out);
}